// Round 5
// baseline (671.312 us; speedup 1.0000x reference)
//
#include <hip/hip_runtime.h>
#include <math.h>

#define EPS 1e-6f
#define NE 64
#define TPB 1024
#define WPB 16             // waves per block
#define NBLK 256           // 1 block/CU (persistent residency requires this)
#define NWAVES (NBLK * WPB)   // 4096
#define ITERS 10
#define QPW 32             // quads per wave (131072 / 4096)
#define NR 16              // register-resident quads (exp-precomputed)
#define NL 8               // LDS-resident quads (exp-precomputed, 128 KB dyn)
#define NS 8               // streamed quads per pass (exp recomputed)

// ---- DPP helpers: 16-lane-group reductions, pure VALU (no ds ops) ----
template <int ctrl>
__device__ __forceinline__ float dppf(float x) {
    return __int_as_float(__builtin_amdgcn_update_dpp(
        0, __float_as_int(x), ctrl, 0xf, 0xf, true));
}
template <int ctrl>
__device__ __forceinline__ int dppi(int x) {
    return __builtin_amdgcn_update_dpp(0, x, ctrl, 0xf, 0xf, true);
}

__device__ __forceinline__ float group16_sum(float v) {
    v += dppf<0xB1>(v);   // quad_perm xor 1
    v += dppf<0x4E>(v);   // quad_perm xor 2
    v += dppf<0x141>(v);  // row_half_mirror (xor 4)
    v += dppf<0x140>(v);  // row_mirror (xor 8)
    return v;
}

#define ARGMAX_STEP(CTRL)                                      \
    {                                                          \
        float ov = dppf<CTRL>(v);                              \
        int oi = dppi<CTRL>(i);                                \
        if (ov > v || (ov == v && oi < i)) { v = ov; i = oi; } \
    }

__device__ __forceinline__ void group16_argmax(float& v, int& i) {
    ARGMAX_STEP(0xB1)
    ARGMAX_STEP(0x4E)
    ARGMAX_STEP(0x141)
    ARGMAX_STEP(0x140)
}

// Persistent fused kernel, round 5: on-chip residency.
// R3/R4 post-mortem: per-CU streaming delivery is capped ~5.75 B/cyc/CU
// independent of waves (R3) or prefetch depth (R4) -> L1 miss-path limit.
// Fix: hold exp(logits) on-chip across iterations. Per wave (32 quads):
//   q 0..15  -> VGPRs (16 x float4/lane = 64 regs)
//   q 16..23 -> LDS   (128 KB dynamic/block)
//   q 24..31 -> streamed each pass (4 MB/XCD = L2-resident)
// exp computed ONCE (pass 0) for residents -> bitwise identical (same
// __expf values, same op order/forms per phase as validated R2 kernel).
// Barrier/reduce machinery unchanged from R2 (validated, 403us).
__global__ __launch_bounds__(TPB) void sink_fused(
    const float4* __restrict__ logits4,
    float* __restrict__ Pblk,          // [2][NBLK][NE]
    unsigned* __restrict__ counters,   // [ITERS]
    float2* __restrict__ oidx, float2* __restrict__ ow,
    int nquads, float col_target) {
    extern __shared__ float4 ldsq[];   // [WPB*NL*64] = 128 KB resident data
    __shared__ float4 plds[WPB][64];   // 16 KB  block column-partial buffer
    __shared__ float s_red[16][NE];    // 4 KB   chunk-reduce buffer
    __shared__ float r_lds[WPB * 128]; // 8 KB   per-row r (2048 rows/block)
    __shared__ float4 c_lds4[NE / 4];  // 256 B  current column scaling

    const int tid = threadIdx.x;
    const int lane = tid & 63;
    const int wib = tid >> 6;
    const int g = lane >> 4;   // row within quad
    const int h = lane & 15;   // float4 slot within row
    const int qbase = (blockIdx.x * WPB + wib) * QPW;
    const float4* lp = logits4 + (size_t)qbase * 64 + lane;
    const int lrow0 = wib * 128 + g;

    if (tid < NE / 4) c_lds4[tid] = make_float4(1.f, 1.f, 1.f, 1.f);
    __syncthreads();

    auto exp4 = [](const float4& v) {
        float4 e;
        e.x = __expf(v.x); e.y = __expf(v.y);
        e.z = __expf(v.z); e.w = __expf(v.w);
        return e;
    };

    // per-quad Sinkhorn row step (same expression forms as validated R2)
    auto procq = [&](const float4& e, int q, const float4& c4, float4& pacc,
                     bool first) {
        float s = e.x * c4.x + e.y * c4.y + e.z * c4.z + e.w * c4.w;
        s = group16_sum(s);
        const int lrow = lrow0 + q * 4;
        float rold = first ? 1.0f : r_lds[lrow];
        float rnew = rold / (rold * s + EPS);
        if (h == 0) r_lds[lrow] = rnew;
        pacc.x += e.x * rnew; pacc.y += e.y * rnew;
        pacc.z += e.z * rnew; pacc.w += e.w * rnew;
    };

    // block column-reduce + grid barrier + global reduce + c update
    // (identical structure/order to validated R2 kernel)
    auto col_reduce_barrier = [&](const float4& pacc, int it) {
        float* Pcur = Pblk + (size_t)(it & 1) * NBLK * NE;
        plds[wib][lane] = pacc;
        __syncthreads();
        if (tid < NE) {
            const int hh = tid >> 2, kk = tid & 3;
            float t = 0.f;
#pragma unroll
            for (int w = 0; w < WPB; ++w)
#pragma unroll
                for (int gg = 0; gg < 4; ++gg)
                    t += ((const float*)&plds[w][gg * 16 + hh])[kk];
            __hip_atomic_store(&Pcur[blockIdx.x * NE + tid], t,
                               __ATOMIC_RELAXED, __HIP_MEMORY_SCOPE_AGENT);
        }
        __syncthreads();   // partials drained before arrival
        if (tid == 0) {
            __builtin_amdgcn_fence(__ATOMIC_RELEASE, "agent");
            __hip_atomic_fetch_add(&counters[it], 1u, __ATOMIC_RELAXED,
                                   __HIP_MEMORY_SCOPE_AGENT);
            while (__hip_atomic_load(&counters[it], __ATOMIC_RELAXED,
                                     __HIP_MEMORY_SCOPE_AGENT) < (unsigned)NBLK)
                __builtin_amdgcn_s_sleep(2);
            __builtin_amdgcn_fence(__ATOMIC_ACQUIRE, "agent");
        }
        __syncthreads();
        {
            const int col = tid & 63;
            const int chunk = tid >> 6;          // 16 chunks of 16 blocks
            const int b0 = chunk * (NBLK / 16);
            float t = 0.f;
#pragma unroll
            for (int b2 = 0; b2 < NBLK / 16; ++b2)
                t += __hip_atomic_load(&Pcur[(b0 + b2) * NE + col],
                                       __ATOMIC_RELAXED,
                                       __HIP_MEMORY_SCOPE_AGENT);
            s_red[chunk][col] = t;
        }
        __syncthreads();
        if (tid < NE) {
            float P = 0.f;
#pragma unroll
            for (int k = 0; k < 16; ++k) P += s_red[k][tid];
            float cj = ((float*)c_lds4)[tid];
            ((float*)c_lds4)[tid] = cj * col_target / (cj * P + EPS);
        }
        __syncthreads();
    };

    float4 RD[NR];   // register-resident exp(logits), compile-time indexed

    // ---- pass 0: stream everything, stash exp into RD/LDS -----------------
    {
        const float4 c4 = c_lds4[h];   // all ones
        float4 buf[4];
#pragma unroll
        for (int p = 0; p < 4; ++p) buf[p] = lp[(size_t)p * 64];
        float4 pacc = {0.f, 0.f, 0.f, 0.f};
#pragma unroll
        for (int b = 0; b < 8; ++b) {
            float4 cur[4];
#pragma unroll
            for (int p = 0; p < 4; ++p) cur[p] = buf[p];
            if (b < 7) {
#pragma unroll
                for (int p = 0; p < 4; ++p)
                    buf[p] = lp[(size_t)((b + 1) * 4 + p) * 64];
            }
#pragma unroll
            for (int p = 0; p < 4; ++p) {
                const int q = b * 4 + p;           // compile-time constant
                float4 e = exp4(cur[p]);
                if (q < NR) RD[q] = e;
                else if (q < NR + NL)
                    ldsq[(wib * NL + (q - NR)) * 64 + lane] = e;
                procq(e, q, c4, pacc, true);
            }
        }
        col_reduce_barrier(pacc, 0);
    }

    // ---- passes 1..9: residents + small streamed tail ---------------------
    for (int it = 1; it < ITERS; ++it) {
        const float4 c4 = c_lds4[h];
        float4 sbuf[4];
#pragma unroll
        for (int p = 0; p < 4; ++p) sbuf[p] = lp[(size_t)(24 + p) * 64];

        float4 pacc = {0.f, 0.f, 0.f, 0.f};
#pragma unroll
        for (int q = 0; q < NR; ++q) procq(RD[q], q, c4, pacc, false);

        float4 sbuf2[4];
#pragma unroll
        for (int p = 0; p < 4; ++p) sbuf2[p] = lp[(size_t)(28 + p) * 64];

        // LDS residents, 1-deep pipelined reads
        float4 lcur = ldsq[(wib * NL) * 64 + lane];
#pragma unroll
        for (int j = 0; j < NL; ++j) {
            float4 lnxt;
            if (j + 1 < NL) lnxt = ldsq[(wib * NL + j + 1) * 64 + lane];
            procq(lcur, NR + j, c4, pacc, false);
            lcur = lnxt;
        }
#pragma unroll
        for (int p = 0; p < 4; ++p) procq(exp4(sbuf[p]), 24 + p, c4, pacc, false);
#pragma unroll
        for (int p = 0; p < 4; ++p) procq(exp4(sbuf2[p]), 28 + p, c4, pacc, false);

        col_reduce_barrier(pacc, it);
    }

    // ---- final: row-normalize + top-2 (DPP argmax) + renorm ---------------
    {
        const float4 c4 = c_lds4[h];
        const int base_col = h * 4;

        auto top2 = [&](const float4& e, int q) {
            float4 u;
            u.x = e.x * c4.x; u.y = e.y * c4.y;
            u.z = e.z * c4.z; u.w = e.w * c4.w;
            float s = group16_sum(u.x + u.y + u.z + u.w);
            const int lrow = lrow0 + q * 4;
            float rold = r_lds[lrow];
            float rnew = rold / (rold * s + EPS);
            float4 val;
            val.x = u.x * rnew; val.y = u.y * rnew;
            val.z = u.z * rnew; val.w = u.w * rnew;

            float v = val.x; int i = base_col;
            if (val.y > v) { v = val.y; i = base_col + 1; }
            if (val.z > v) { v = val.z; i = base_col + 2; }
            if (val.w > v) { v = val.w; i = base_col + 3; }
            group16_argmax(v, i);
            float v1 = v; int i1 = i;

            float4 mv;
            mv.x = (i1 == base_col)     ? -INFINITY : val.x;
            mv.y = (i1 == base_col + 1) ? -INFINITY : val.y;
            mv.z = (i1 == base_col + 2) ? -INFINITY : val.z;
            mv.w = (i1 == base_col + 3) ? -INFINITY : val.w;
            v = mv.x; i = base_col;
            if (mv.y > v) { v = mv.y; i = base_col + 1; }
            if (mv.z > v) { v = mv.z; i = base_col + 2; }
            if (mv.w > v) { v = mv.w; i = base_col + 3; }
            group16_argmax(v, i);
            float v2 = v; int i2 = i;

            if (h == 0) {
                int row = (qbase + q) * 4 + g;
                float wsum = v1 + v2 + EPS;
                oidx[row] = make_float2((float)i1, (float)i2);
                ow[row] = make_float2(v1 / wsum, v2 / wsum);
            }
        };

        float4 sbuf[4];
#pragma unroll
        for (int p = 0; p < 4; ++p) sbuf[p] = lp[(size_t)(24 + p) * 64];

#pragma unroll
        for (int q = 0; q < NR; ++q) top2(RD[q], q);

        float4 sbuf2[4];
#pragma unroll
        for (int p = 0; p < 4; ++p) sbuf2[p] = lp[(size_t)(28 + p) * 64];

        float4 lcur = ldsq[(wib * NL) * 64 + lane];
#pragma unroll
        for (int j = 0; j < NL; ++j) {
            float4 lnxt;
            if (j + 1 < NL) lnxt = ldsq[(wib * NL + j + 1) * 64 + lane];
            top2(lcur, NR + j);
            lcur = lnxt;
        }
#pragma unroll
        for (int p = 0; p < 4; ++p) top2(exp4(sbuf[p]), 24 + p);
#pragma unroll
        for (int p = 0; p < 4; ++p) top2(exp4(sbuf2[p]), 28 + p);
    }
}

extern "C" void kernel_launch(void* const* d_in, const int* in_sizes, int n_in,
                              void* d_out, int out_size, void* d_ws, size_t ws_size,
                              hipStream_t stream) {
    const float* logits = (const float*)d_in[0];
    const int S = in_sizes[0] / NE;            // 524288
    const int nquads = S / 4;                  // 131072 (divisible by NWAVES)
    const float col_target = (float)S / (float)NE;

    float* Pblk = (float*)d_ws;                // 2*NBLK*64 floats (dbuf)
    unsigned* counters = (unsigned*)(Pblk + 2 * NBLK * NE);  // ITERS slots

    float* out = (float*)d_out;
    float2* oidx = (float2*)out;               // 2*S floats (indices)
    float2* ow = (float2*)(out + (size_t)2 * S);  // 2*S floats (weights)

    const size_t dyn_lds = (size_t)WPB * NL * 64 * sizeof(float4);  // 128 KB
    static bool attr_done = false;
    if (!attr_done) {
        hipFuncSetAttribute(reinterpret_cast<const void*>(sink_fused),
                            hipFuncAttributeMaxDynamicSharedMemorySize,
                            (int)dyn_lds);
        attr_done = true;
    }

    hipMemsetAsync(counters, 0, ITERS * sizeof(unsigned), stream);
    sink_fused<<<NBLK, TPB, dyn_lds, stream>>>((const float4*)logits, Pblk,
                                               counters, oidx, ow, nquads,
                                               col_target);
}